// Round 9
// baseline (5032.162 us; speedup 1.0000x reference)
//
#include <hip/hip_runtime.h>

#define BB 4
#define NN 16384
#define CC 64
#define NPOINT 1024
#define NSAMPLE 32

#define NCHUNK 256          // 64 points per chunk
#define NCELL 4096          // 16^3 Morton cells

#define REPEAT64(M) \
  M(0) M(1) M(2) M(3) M(4) M(5) M(6) M(7) M(8) M(9) \
  M(10) M(11) M(12) M(13) M(14) M(15) M(16) M(17) M(18) M(19) \
  M(20) M(21) M(22) M(23) M(24) M(25) M(26) M(27) M(28) M(29) \
  M(30) M(31) M(32) M(33) M(34) M(35) M(36) M(37) M(38) M(39) \
  M(40) M(41) M(42) M(43) M(44) M(45) M(46) M(47) M(48) M(49) \
  M(50) M(51) M(52) M(53) M(54) M(55) M(56) M(57) M(58) M(59) \
  M(60) M(61) M(62) M(63)

#define GRP8(M,a,b,c,d,e,f,g,h) M(a) M(b) M(c) M(d) M(e) M(f) M(g) M(h)

// ---------------------------------------------------------------------------
// K0: setup — Morton counting-sort into sb (float4 x,y,z,origidx-bits) and
// per-chunk AABBs into aw. 1024 threads per batch.
// ---------------------------------------------------------------------------
__global__ __launch_bounds__(1024) void fps_setup(const float* __restrict__ xyz,
                                                  float4* __restrict__ sorted,
                                                  float* __restrict__ aw) {
    __shared__ int hist[NCELL];
    __shared__ int wsum[16];

    const int b    = blockIdx.x;
    const int tid  = threadIdx.x;
    const int lane = tid & 63;
    const int wv   = tid >> 6;
    const float* bx = xyz + (size_t)b * NN * 3;
    float4* sb = sorted + (size_t)b * NN;

    #pragma unroll
    for (int j = 0; j < 4; ++j) hist[j * 1024 + tid] = 0;
    __syncthreads();

    #pragma unroll
    for (int j = 0; j < 16; ++j) {
        const int p = j * 1024 + tid;
        const float x = bx[p * 3 + 0], y = bx[p * 3 + 1], z = bx[p * 3 + 2];
        int cx = (int)(x * 16.0f); cx = cx > 15 ? 15 : (cx < 0 ? 0 : cx);
        int cy = (int)(y * 16.0f); cy = cy > 15 ? 15 : (cy < 0 ? 0 : cy);
        int cz = (int)(z * 16.0f); cz = cz > 15 ? 15 : (cz < 0 ? 0 : cz);
        int code = 0;
        #pragma unroll
        for (int i = 0; i < 4; ++i)
            code |= (((cx >> i) & 1) << (3 * i)) |
                    (((cy >> i) & 1) << (3 * i + 1)) |
                    (((cz >> i) & 1) << (3 * i + 2));
        atomicAdd(&hist[code], 1);
    }
    __syncthreads();

    {
        const int h0 = hist[4 * tid + 0], h1 = hist[4 * tid + 1];
        const int h2 = hist[4 * tid + 2], h3 = hist[4 * tid + 3];
        const int s  = h0 + h1 + h2 + h3;
        int v = s;
        #pragma unroll
        for (int o = 1; o < 64; o <<= 1) {
            const int u = __shfl_up(v, o, 64);
            if (lane >= o) v += u;
        }
        if (lane == 63) wsum[wv] = v;
        __syncthreads();
        int base = 0;
        for (int w = 0; w < wv; ++w) base += wsum[w];
        const int e0 = base + v - s;
        hist[4 * tid + 0] = e0;
        hist[4 * tid + 1] = e0 + h0;
        hist[4 * tid + 2] = e0 + h0 + h1;
        hist[4 * tid + 3] = e0 + h0 + h1 + h2;
    }
    __syncthreads();

    #pragma unroll
    for (int j = 0; j < 16; ++j) {
        const int p = j * 1024 + tid;
        const float x = bx[p * 3 + 0], y = bx[p * 3 + 1], z = bx[p * 3 + 2];
        int cx = (int)(x * 16.0f); cx = cx > 15 ? 15 : (cx < 0 ? 0 : cx);
        int cy = (int)(y * 16.0f); cy = cy > 15 ? 15 : (cy < 0 ? 0 : cy);
        int cz = (int)(z * 16.0f); cz = cz > 15 ? 15 : (cz < 0 ? 0 : cz);
        int code = 0;
        #pragma unroll
        for (int i = 0; i < 4; ++i)
            code |= (((cx >> i) & 1) << (3 * i)) |
                    (((cy >> i) & 1) << (3 * i + 1)) |
                    (((cz >> i) & 1) << (3 * i + 2));
        const int slot = atomicAdd(&hist[code], 1);
        sb[slot] = make_float4(x, y, z, __int_as_float(p));
    }
    __syncthreads();   // drains scatter stores before readback

    for (int g = wv; g < NCHUNK; g += 16) {
        const float4 pt = sb[g * 64 + lane];
        float mnx = pt.x, mxx = pt.x, mny = pt.y, mxy = pt.y, mnz = pt.z, mxz = pt.z;
        #pragma unroll
        for (int m = 32; m >= 1; m >>= 1) {
            mnx = fminf(mnx, __shfl_xor(mnx, m, 64));
            mxx = fmaxf(mxx, __shfl_xor(mxx, m, 64));
            mny = fminf(mny, __shfl_xor(mny, m, 64));
            mxy = fmaxf(mxy, __shfl_xor(mxy, m, 64));
            mnz = fminf(mnz, __shfl_xor(mnz, m, 64));
            mxz = fmaxf(mxz, __shfl_xor(mxz, m, 64));
        }
        if (lane == 0) {
            float* a = aw + ((size_t)b * NCHUNK + g) * 6;
            a[0] = mnx; a[1] = mxx; a[2] = mny; a[3] = mxy; a[4] = mnz; a[5] = mxz;
        }
    }
}

// ---------------------------------------------------------------------------
// K1: FPS main loop. 256 threads (4 waves) per batch.
// Wave wv owns chunks [(wv<<6), (wv<<6)+64); lane L holds the u64 key
// (d_bits<<32 | 0x3FFF-orig) of point (chunk, position L) in 64 NAMED
// REGISTERS key0..key63. Lane L also AABB-tests chunk (wv<<6)+L.
// Event-driven reductions: per-lane best recomputed only when its best key
// decreased; per-wave butterfly only when the holder lane's best decreased.
// Cross-wave: holder ds_writes record, ONE barrier, all read 4 slots.
// Prune: chunk skipped iff mind2(AABB,c) > prev_winner_d*1.001 (keys only
// decrease and chunk max <= global max -> skip is an exact no-op).
// Bit-exact: contract(off), (dx*dx+dy*dy)+dz*dz, min-as-conditional-update,
// ties -> smallest original index via tb in key (keys globally unique).
// ---------------------------------------------------------------------------
__global__ __launch_bounds__(256, 1) void fps_main(const float* __restrict__ xyz,
                                                   const float4* __restrict__ sorted,
                                                   const float* __restrict__ aw,
                                                   float* __restrict__ new_xyz) {
    #pragma clang fp contract(off)
    __shared__ float4 wb4[2][4];
    __shared__ unsigned long long wbk[2][4];

    const int b    = blockIdx.x;
    const int tid  = threadIdx.x;
    const int lane = tid & 63;
    const int wv   = tid >> 6;                  // 0..3
    const float* bx = xyz + (size_t)b * NN * 3;
    const float4* sb = sorted + (size_t)b * NN;

    // AABB of my test-chunk (wv<<6)+lane
    const float* ap = aw + ((size_t)b * NCHUNK + (wv << 6) + lane) * 6;
    const float abx0 = ap[0], abx1 = ap[1];
    const float aby0 = ap[2], aby1 = ap[3];
    const float abz0 = ap[4], abz1 = ap[5];

#define DECLK(k) unsigned long long key##k = \
    ((unsigned long long)__float_as_uint(1e10f)) << 32;
    REPEAT64(DECLK)
#undef DECLK

    unsigned long long bkey = 0ull;   // my lane best (max over key0..63)
    int bestk = 0;                    // chunk-within-wave of my best
    int holder_ln = 0;                // wave-uniform: lane holding wave best
    float hx = bx[0], hy = bx[1], hz = bx[2];   // holder's best coords

    float ccx = bx[0], ccy = bx[1], ccz = bx[2];
    float prev_wd = 1e10f;
    float* outb = new_xyz + (size_t)b * NPOINT * 3;

    for (int it = 0; it < NPOINT; ++it) {
        if (tid == 0) {
            outb[it * 3 + 0] = ccx;
            outb[it * 3 + 1] = ccy;
            outb[it * 3 + 2] = ccz;
        }

        // --- AABB prune (lane L -> chunk (wv<<6)+L), all registers ---
        const float tdx = fmaxf(fmaxf(abx0 - ccx, ccx - abx1), 0.0f);
        const float tdy = fmaxf(fmaxf(aby0 - ccy, ccy - aby1), 0.0f);
        const float tdz = fmaxf(fmaxf(abz0 - ccz, ccz - abz1), 0.0f);
        const float mind2 = tdx * tdx + tdy * tdy + tdz * tdz;
        const bool active = !(mind2 > prev_wd * 1.001f);
        const unsigned long long amask = __ballot(active);

        bool lredo = false;

        // --- update active chunks; 8-group guards skip idle regions fast ---
#define UPD(k) if (amask & (1ull << (k))) {                               \
            const float4 pt = sb[((((wv) << 6) + (k)) << 6) + lane];      \
            const float dx = pt.x - ccx;                                  \
            const float dy = pt.y - ccy;                                  \
            const float dz = pt.z - ccz;                                  \
            const float t  = (dx * dx + dy * dy) + dz * dz;               \
            const float dold = __uint_as_float((unsigned)(key##k >> 32)); \
            if (t < dold) {                                               \
                key##k = (((unsigned long long)__float_as_uint(t)) << 32) \
                    | (unsigned long long)(0x3FFFu -                      \
                                (unsigned)__float_as_int(pt.w));          \
                lredo |= ((k) == bestk);                                  \
            }                                                             \
        }
        if (amask & 0x00000000000000FFull) { GRP8(UPD, 0, 1, 2, 3, 4, 5, 6, 7) }
        if (amask & 0x000000000000FF00ull) { GRP8(UPD, 8, 9,10,11,12,13,14,15) }
        if (amask & 0x0000000000FF0000ull) { GRP8(UPD,16,17,18,19,20,21,22,23) }
        if (amask & 0x00000000FF000000ull) { GRP8(UPD,24,25,26,27,28,29,30,31) }
        if (amask & 0x000000FF00000000ull) { GRP8(UPD,32,33,34,35,36,37,38,39) }
        if (amask & 0x0000FF0000000000ull) { GRP8(UPD,40,41,42,43,44,45,46,47) }
        if (amask & 0x00FF000000000000ull) { GRP8(UPD,48,49,50,51,52,53,54,55) }
        if (amask & 0xFF00000000000000ull) { GRP8(UPD,56,57,58,59,60,61,62,63) }
#undef UPD

        // --- per-lane best: recompute only when invalidated ---
        if (lredo) {
            bkey = 0ull; bestk = 0;
#define LM(k) if (key##k > bkey) { bkey = key##k; bestk = (k); }
            REPEAT64(LM)
#undef LM
        }

        // --- wave best: butterfly only when holder's best decreased ---
        const unsigned long long rb = __ballot(lredo);
        if ((rb >> holder_ln) & 1ull) {
            unsigned long long m = bkey;
            #pragma unroll
            for (int s = 32; s >= 1; s >>= 1) {
                const unsigned long long o = __shfl_xor(m, s, 64);
                m = o > m ? o : m;
            }
            holder_ln = __ffsll((long long)__ballot(bkey == m)) - 1;
            if (lane == holder_ln) {
                const float4 pt = sb[((((wv) << 6) + bestk) << 6) + lane];
                hx = pt.x; hy = pt.y; hz = pt.z;
            }
        }

        // --- cross-wave exchange: 1 write, 1 barrier, 4 reads ---
        if (lane == holder_ln) {
            wb4[it & 1][wv] = make_float4(hx, hy, hz, 0.0f);
            wbk[it & 1][wv] = bkey;
        }
        __syncthreads();

        const unsigned long long k0 = wbk[it & 1][0];
        const unsigned long long k1 = wbk[it & 1][1];
        const unsigned long long k2 = wbk[it & 1][2];
        const unsigned long long k3 = wbk[it & 1][3];
        const float4 f0 = wb4[it & 1][0];
        const float4 f1 = wb4[it & 1][1];
        const float4 f2 = wb4[it & 1][2];
        const float4 f3 = wb4[it & 1][3];

        unsigned long long wk = k0; float4 wf = f0;
        if (k1 > wk) { wk = k1; wf = f1; }
        if (k2 > wk) { wk = k2; wf = f2; }
        if (k3 > wk) { wk = k3; wf = f3; }

        prev_wd = __uint_as_float((unsigned)(wk >> 32));
        ccx = wf.x; ccy = wf.y; ccz = wf.z;
    }
}

// ---------------------------------------------------------------------------
// K2: Ball query. One wave per query; ordered first-32 selection via ballot,
// early exit once 32 found. Exact arithmetic (contract off, rad2 = (float)0.04).
// ---------------------------------------------------------------------------
__global__ __launch_bounds__(256) void ballq_kernel(const float* __restrict__ xyz,
                                                    const float* __restrict__ new_xyz,
                                                    int* __restrict__ gidx) {
    #pragma clang fp contract(off)
    const int lane = threadIdx.x & 63;
    const int q    = blockIdx.x * 4 + (threadIdx.x >> 6);
    const int b    = q >> 10;                  // NPOINT = 1024
    const float* bx = xyz + (size_t)b * NN * 3;
    const float* nx = new_xyz + (size_t)q * 3;
    const float cx = nx[0], cy = nx[1], cz = nx[2];
    const float rad2 = 0.04f;  // f32 cast of python double 0.2**2 — NOT 0.2f*0.2f

    int* out  = gidx + (size_t)q * NSAMPLE;
    int taken = 0;
    int first = NN - 1;

    for (int chunk = 0; chunk < NN / 64 && taken < NSAMPLE; ++chunk) {
        const int   i  = chunk * 64 + lane;
        const float dx = cx - bx[i * 3 + 0];
        const float dy = cy - bx[i * 3 + 1];
        const float dz = cz - bx[i * 3 + 2];
        const float t  = dx * dx + dy * dy + dz * dz;
        const bool ok  = !(t > rad2);
        const unsigned long long m = __ballot(ok);
        const int cnt = __popcll(m);
        if (taken == 0 && cnt > 0) first = chunk * 64 + (__ffsll((long long)m) - 1);
        if (ok) {
            const int rank = taken + __popcll(m & ((1ull << lane) - 1ull));
            if (rank < NSAMPLE) out[rank] = i;
        }
        taken += cnt;
    }
    const int sat = taken < NSAMPLE ? taken : NSAMPLE;
    if (lane >= sat && lane < NSAMPLE) out[lane] = (taken > 0) ? first : (NN - 1);
}

// ---------------------------------------------------------------------------
// K3: gather feats -> LDS, MLP1 (67->64) + relu, MLP2 (64->128) + relu,
// max over the 32 samples. One 256-thread block per query. FMA allowed.
// ---------------------------------------------------------------------------
__global__ __launch_bounds__(256) void mlp_kernel(const float* __restrict__ xyz,
                                                  const float* __restrict__ points,
                                                  const float* __restrict__ w1,
                                                  const float* __restrict__ b1,
                                                  const float* __restrict__ w2,
                                                  const float* __restrict__ b2,
                                                  const float* __restrict__ new_xyz,
                                                  const int*   __restrict__ gidx,
                                                  float* __restrict__ new_points) {
    __shared__ __align__(16) float feats[32][68];
    __shared__ __align__(16) float h1s[32][64];
    __shared__ float pmax[2][128];

    const int q = blockIdx.x;
    const int b = q >> 10;
    const int t = threadIdx.x;

    {
        const int k  = t >> 3;
        const int l8 = t & 7;
        const int gi = gidx[q * 32 + k];
        const float* prow = points + ((size_t)b * NN + gi) * CC;
        const float4 v0 = *(const float4*)(prow + l8 * 8);
        const float4 v1 = *(const float4*)(prow + l8 * 8 + 4);
        *(float4*)&feats[k][4 + l8 * 8] = v0;
        *(float4*)&feats[k][8 + l8 * 8] = v1;
        if (l8 == 0) {
            const float* pr = xyz + ((size_t)b * NN + gi) * 3;
            const float* nr = new_xyz + (size_t)q * 3;
            feats[k][0] = pr[0] - nr[0];
            feats[k][1] = pr[1] - nr[1];
            feats[k][2] = pr[2] - nr[2];
        }
    }

    const int c1 = t & 63;
    float w1r[67];
    #pragma unroll
    for (int j = 0; j < 67; ++j) w1r[j] = w1[c1 * 67 + j];
    const float bb1 = b1[c1];
    __syncthreads();

    const int kg = t >> 6;
    #pragma unroll
    for (int kk = 0; kk < 8; ++kk) {
        const int kr = kg * 8 + kk;
        float acc = bb1;
        acc += feats[kr][0] * w1r[0] + feats[kr][1] * w1r[1] + feats[kr][2] * w1r[2];
        #pragma unroll
        for (int j = 0; j < 64; j += 4) {
            const float4 f = *(const float4*)&feats[kr][4 + j];
            acc += f.x * w1r[3 + j] + f.y * w1r[4 + j] + f.z * w1r[5 + j] + f.w * w1r[6 + j];
        }
        h1s[kr][c1] = fmaxf(acc, 0.0f);
    }

    const int o2 = t & 127;
    const int kh = t >> 7;
    float w2r[64];
    #pragma unroll
    for (int j = 0; j < 64; ++j) w2r[j] = w2[o2 * 64 + j];
    const float bb2 = b2[o2];
    __syncthreads();

    float mx = -INFINITY;
    #pragma unroll
    for (int kk = 0; kk < 16; ++kk) {
        const int kr = kh * 16 + kk;
        float acc = bb2;
        #pragma unroll
        for (int j = 0; j < 64; j += 4) {
            const float4 h = *(const float4*)&h1s[kr][j];
            acc += h.x * w2r[j] + h.y * w2r[j + 1] + h.z * w2r[j + 2] + h.w * w2r[j + 3];
        }
        mx = fmaxf(mx, fmaxf(acc, 0.0f));
    }
    pmax[kh][o2] = mx;
    __syncthreads();
    if (t < 128) {
        new_points[(size_t)q * 128 + t] = fmaxf(pmax[0][t], pmax[1][t]);
    }
}

// ---------------------------------------------------------------------------
extern "C" void kernel_launch(void* const* d_in, const int* in_sizes, int n_in,
                              void* d_out, int out_size, void* d_ws, size_t ws_size,
                              hipStream_t stream) {
    const float* xyz    = (const float*)d_in[0];
    const float* points = (const float*)d_in[1];
    const float* w1     = (const float*)d_in[2];
    const float* b1     = (const float*)d_in[3];
    const float* w2     = (const float*)d_in[4];
    const float* b2     = (const float*)d_in[5];

    float* out_newxyz    = (float*)d_out;
    float* out_newpoints = (float*)d_out + (size_t)BB * NPOINT * 3;
    int*    gidx    = (int*)d_ws;                                     // 512 KB
    float4* sortbuf = (float4*)((char*)d_ws + (size_t)512 * 1024);    // 1 MB
    float*  aabbw   = (float*)((char*)d_ws + (size_t)(512 + 1024) * 1024); // 24 KB

    fps_setup<<<BB, 1024, 0, stream>>>(xyz, sortbuf, aabbw);
    fps_main<<<BB, 256, 0, stream>>>(xyz, sortbuf, aabbw, out_newxyz);
    ballq_kernel<<<(BB * NPOINT) / 4, 256, 0, stream>>>(xyz, out_newxyz, gidx);
    mlp_kernel<<<BB * NPOINT, 256, 0, stream>>>(xyz, points, w1, b1, w2, b2,
                                                out_newxyz, gidx, out_newpoints);
}

// Round 10
// 1800.117 us; speedup vs baseline: 2.7955x; 2.7955x over previous
//
#include <hip/hip_runtime.h>

#define BB 4
#define NN 16384
#define CC 64
#define NPOINT 1024
#define NSAMPLE 32

#define FPS_T 1024
#define NCHUNK 256          // 64 points per chunk
#define NCELL 4096          // 16^3 Morton cells

#define REPEAT16(M) M(0) M(1) M(2) M(3) M(4) M(5) M(6) M(7) \
                    M(8) M(9) M(10) M(11) M(12) M(13) M(14) M(15)

#define PAD(g) ((g) + ((g) >> 4))

// ---------------------------------------------------------------------------
// K1: Pruned FPS, 16 waves, event-driven reductions, no global ops and no
// LDS atomics in the iteration loop.
//  - Morton counting-sort: sb (global, float4 x,y,z,orig) + sxy (LDS float2).
//  - Wave wv owns chunks {wv+16k}; lane L holds u64 key##k =
//    d_bits<<32 | (0x3FFF-orig) of point (chunk,L) — LOOP-CARRIED (cannot be
//    rematerialized; R9 verified). z##k asm-pinned. AABB in lane-k regs.
//  - Prune: chunk active iff mind2(AABB,c) <= prev_winner_d*1.001 (keys only
//    decrease, chunk max <= global max -> skip is an exact no-op).
//  - Event-driven: lane best recomputed only when its best's key decreased;
//    wave butterfly only when holder lane's best decreased. Keys are unique
//    (tb) -> no tie paths anywhere; first-original-index tie-break exact.
//  - Exchange: holder writes {key,coords} to dbuf slot (cached regs, every
//    iter); ONE barrier; final reduce = 1 ds_read (slot lane&15) + 4-level
//    u64 butterfly + 1 broadcast coords read.
//  - Centroids buffered in LDS outc[] -> the pre-barrier s_waitcnt has no
//    vmcnt component (no global stores in flight); flushed after the loop.
// Bit-exact: contract(off), (dx*dx+dy*dy)+dz*dz order, min-as-cond-update.
// ---------------------------------------------------------------------------
__global__ __launch_bounds__(FPS_T) void fps_kernel(const float* __restrict__ xyz,
                                                    float* __restrict__ new_xyz,
                                                    float4* __restrict__ sorted) {
    #pragma clang fp contract(off)
    extern __shared__ char smem_raw[];
    float2* sxy  = (float2*)smem_raw;                         // 131072 B
    int*    hist = (int*)(smem_raw + 131072);                 // 16384 B (setup)
    float*  outc = (float*)(smem_raw + 131072);               // 12288 B (alias)
    float*  lox  = (float*)(smem_raw + 147456);               // 272 f x6
    float*  loy  = lox + 272;
    float*  loz  = loy + 272;
    float*  hix  = loz + 272;
    float*  hiy  = hix + 272;
    float*  hiz  = hiy + 272;
    unsigned long long* wbk = (unsigned long long*)(smem_raw + 153984); // [2][16]
    float4* wbc  = (float4*)(smem_raw + 154240);              // [2][16]
    int*    wsum = (int*)(smem_raw + 154752);                 // [16]

    const int b    = blockIdx.x;
    const int tid  = threadIdx.x;
    const int lane = tid & 63;
    const int wv   = tid >> 6;                  // 0..15
    const float* bx = xyz + (size_t)b * NN * 3;
    float4* sb = sorted + (size_t)b * NN;

    // ---------- phase 0a: histogram of Morton cell codes ----------
    #pragma unroll
    for (int j = 0; j < 4; ++j) hist[j * FPS_T + tid] = 0;
    __syncthreads();

    #pragma unroll
    for (int j = 0; j < 16; ++j) {
        const int p = j * FPS_T + tid;
        const float x = bx[p * 3 + 0], y = bx[p * 3 + 1], z = bx[p * 3 + 2];
        int cx = (int)(x * 16.0f); cx = cx > 15 ? 15 : (cx < 0 ? 0 : cx);
        int cy = (int)(y * 16.0f); cy = cy > 15 ? 15 : (cy < 0 ? 0 : cy);
        int cz = (int)(z * 16.0f); cz = cz > 15 ? 15 : (cz < 0 ? 0 : cz);
        int code = 0;
        #pragma unroll
        for (int i = 0; i < 4; ++i)
            code |= (((cx >> i) & 1) << (3 * i)) |
                    (((cy >> i) & 1) << (3 * i + 1)) |
                    (((cz >> i) & 1) << (3 * i + 2));
        atomicAdd(&hist[code], 1);
    }
    __syncthreads();

    // ---------- phase 0b: exclusive scan ----------
    {
        const int h0 = hist[4 * tid + 0], h1 = hist[4 * tid + 1];
        const int h2 = hist[4 * tid + 2], h3 = hist[4 * tid + 3];
        const int s  = h0 + h1 + h2 + h3;
        int v = s;
        #pragma unroll
        for (int o = 1; o < 64; o <<= 1) {
            const int u = __shfl_up(v, o, 64);
            if (lane >= o) v += u;
        }
        if (lane == 63) wsum[wv] = v;
        __syncthreads();
        int base = 0;
        for (int w = 0; w < wv; ++w) base += wsum[w];
        const int e0 = base + v - s;
        hist[4 * tid + 0] = e0;
        hist[4 * tid + 1] = e0 + h0;
        hist[4 * tid + 2] = e0 + h0 + h1;
        hist[4 * tid + 3] = e0 + h0 + h1 + h2;
    }
    __syncthreads();

    // ---------- phase 0c: scatter to global sb AND LDS sxy ----------
    #pragma unroll
    for (int j = 0; j < 16; ++j) {
        const int p = j * FPS_T + tid;
        const float x = bx[p * 3 + 0], y = bx[p * 3 + 1], z = bx[p * 3 + 2];
        int cx = (int)(x * 16.0f); cx = cx > 15 ? 15 : (cx < 0 ? 0 : cx);
        int cy = (int)(y * 16.0f); cy = cy > 15 ? 15 : (cy < 0 ? 0 : cy);
        int cz = (int)(z * 16.0f); cz = cz > 15 ? 15 : (cz < 0 ? 0 : cz);
        int code = 0;
        #pragma unroll
        for (int i = 0; i < 4; ++i)
            code |= (((cx >> i) & 1) << (3 * i)) |
                    (((cy >> i) & 1) << (3 * i + 1)) |
                    (((cz >> i) & 1) << (3 * i + 2));
        const int slot = atomicAdd(&hist[code], 1);
        sb[slot]  = make_float4(x, y, z, __int_as_float(p));
        sxy[slot] = make_float2(x, y);
    }
    __syncthreads();   // drains scatter stores before readback

    // ---------- phase 0d: per-chunk AABB + z/key preload ----------
#define DECLZ(k) float z##k; unsigned long long key##k;
    REPEAT16(DECLZ)
#undef DECLZ
    float abx0 = 0.f, aby0 = 0.f, abz0 = 0.f, abx1 = 0.f, aby1 = 0.f, abz1 = 0.f;

#define AABBPRE(k) { const int g = wv + ((k) << 4);                       \
    const float4 pt = sb[(g << 6) + lane];                                \
    z##k = pt.z;                                                          \
    key##k = (((unsigned long long)__float_as_uint(1e10f)) << 32) |       \
             (unsigned long long)(0x3FFFu - (unsigned)__float_as_int(pt.w)); \
    float mnx = pt.x, mxx = pt.x, mny = pt.y, mxy = pt.y,                 \
          mnz = pt.z, mxz = pt.z;                                         \
    _Pragma("unroll")                                                     \
    for (int m = 32; m >= 1; m >>= 1) {                                   \
        mnx = fminf(mnx, __shfl_xor(mnx, m, 64));                         \
        mxx = fmaxf(mxx, __shfl_xor(mxx, m, 64));                         \
        mny = fminf(mny, __shfl_xor(mny, m, 64));                         \
        mxy = fmaxf(mxy, __shfl_xor(mxy, m, 64));                         \
        mnz = fminf(mnz, __shfl_xor(mnz, m, 64));                         \
        mxz = fmaxf(mxz, __shfl_xor(mxz, m, 64));                         \
    }                                                                     \
    if (lane == (k)) { abx0 = mnx; abx1 = mxx; aby0 = mny; aby1 = mxy;    \
                       abz0 = mnz; abz1 = mxz; } }
    REPEAT16(AABBPRE)
#undef AABBPRE
    __syncthreads();

    // ---------- main loop ----------
    unsigned long long bkey = 0ull;   // my lane best (max over key0..15)
    int bestk = 0;
    int holder_ln = 0;                // wave-uniform
    float hx = 0.f, hy = 0.f, hz = 0.f;

    float ccx = bx[0], ccy = bx[1], ccz = bx[2];
    float prev_wd = 1e10f;

    for (int it = 0; it < NPOINT; ++it) {
        asm volatile("" : "+v"(z0), "+v"(z1), "+v"(z2),  "+v"(z3),
                          "+v"(z4), "+v"(z5), "+v"(z6),  "+v"(z7),
                          "+v"(z8), "+v"(z9), "+v"(z10), "+v"(z11),
                          "+v"(z12), "+v"(z13), "+v"(z14), "+v"(z15));

        if (tid == 0) {
            outc[it * 3 + 0] = ccx;
            outc[it * 3 + 1] = ccy;
            outc[it * 3 + 2] = ccz;
        }

        // --- AABB prune (lane k -> chunk wv+16k), all registers ---
        bool active = false;
        if (lane < 16) {
            const float dx = fmaxf(fmaxf(abx0 - ccx, ccx - abx1), 0.0f);
            const float dy = fmaxf(fmaxf(aby0 - ccy, ccy - aby1), 0.0f);
            const float dz = fmaxf(fmaxf(abz0 - ccz, ccz - abz1), 0.0f);
            const float mind2 = dx * dx + dy * dy + dz * dz;
            active = !(mind2 > prev_wd * 1.001f);
        }
        const unsigned amask = (unsigned)(__ballot(active) & 0xFFFFull);

        bool lredo = false;
#define UPD(k) if (amask & (1u << (k))) {                                 \
            const int g = wv + ((k) << 4);                                \
            const float2 xy = sxy[(g << 6) + lane];                       \
            const float dx = xy.x - ccx;                                  \
            const float dy = xy.y - ccy;                                  \
            const float dz = z##k - ccz;                                  \
            const float t  = (dx * dx + dy * dy) + dz * dz;               \
            const float dold = __uint_as_float((unsigned)(key##k >> 32)); \
            if (t < dold) {                                               \
                key##k = (((unsigned long long)__float_as_uint(t)) << 32) \
                         | (key##k & 0xFFFFFFFFull);                      \
                lredo |= ((k) == bestk);                                  \
            }                                                             \
        }
        if (amask & 0x000Fu) { UPD(0)  UPD(1)  UPD(2)  UPD(3)  }
        if (amask & 0x00F0u) { UPD(4)  UPD(5)  UPD(6)  UPD(7)  }
        if (amask & 0x0F00u) { UPD(8)  UPD(9)  UPD(10) UPD(11) }
        if (amask & 0xF000u) { UPD(12) UPD(13) UPD(14) UPD(15) }
#undef UPD

        // --- per-lane best: recompute only when invalidated ---
        if (lredo) {
            bkey = 0ull; bestk = 0;
#define LM(k) if (key##k > bkey) { bkey = key##k; bestk = (k); }
            REPEAT16(LM)
#undef LM
        }

        // --- wave best: butterfly only when holder's best decreased ---
        const unsigned long long rb = __ballot(lredo);
        if ((rb >> holder_ln) & 1ull) {
            unsigned long long m = bkey;
            #pragma unroll
            for (int s = 32; s >= 1; s >>= 1) {
                const unsigned long long o = __shfl_xor(m, s, 64);
                m = o > m ? o : m;
            }
            holder_ln = __ffsll((long long)__ballot(bkey == m)) - 1;  // unique
            if (lane == holder_ln) {
                const float2 xy = sxy[((wv + (bestk << 4)) << 6) + lane];
                float zz = z0;
#define ZS(k) zz = (bestk == (k)) ? z##k : zz;
                REPEAT16(ZS)
#undef ZS
                hx = xy.x; hy = xy.y; hz = zz;
            }
        }

        // --- exchange: holder writes cached record every iter (dbuf) ---
        if (lane == holder_ln) {
            wbk[(it & 1) * 16 + wv] = bkey;
            wbc[(it & 1) * 16 + wv] = make_float4(hx, hy, hz, 0.0f);
        }
        __syncthreads();

        // --- global reduce: 1 read + 4-level u64 butterfly + 1 coord read ---
        unsigned long long kk = wbk[(it & 1) * 16 + (lane & 15)];
        int widx = lane & 15;
        #pragma unroll
        for (int s = 8; s >= 1; s >>= 1) {
            const unsigned long long ok = __shfl_xor(kk, s, 64);
            const int oi = __shfl_xor(widx, s, 64);
            if (ok > kk) { kk = ok; widx = oi; }
        }
        prev_wd = __uint_as_float((unsigned)(kk >> 32));
        const float4 wf = wbc[(it & 1) * 16 + widx];
        ccx = wf.x; ccy = wf.y; ccz = wf.z;
    }

    // ---------- flush centroids ----------
    __syncthreads();
    float* outb = new_xyz + (size_t)b * NPOINT * 3;
    #pragma unroll
    for (int j = 0; j < 3; ++j) {
        const int idx = j * FPS_T + tid;
        outb[idx] = outc[idx];
    }
}

// ---------------------------------------------------------------------------
// K2: Ball query. One wave per query; ordered first-32 selection via ballot,
// early exit once 32 found. Exact arithmetic (contract off, rad2 = (float)0.04).
// ---------------------------------------------------------------------------
__global__ __launch_bounds__(256) void ballq_kernel(const float* __restrict__ xyz,
                                                    const float* __restrict__ new_xyz,
                                                    int* __restrict__ gidx) {
    #pragma clang fp contract(off)
    const int lane = threadIdx.x & 63;
    const int q    = blockIdx.x * 4 + (threadIdx.x >> 6);
    const int b    = q >> 10;                  // NPOINT = 1024
    const float* bx = xyz + (size_t)b * NN * 3;
    const float* nx = new_xyz + (size_t)q * 3;
    const float cx = nx[0], cy = nx[1], cz = nx[2];
    const float rad2 = 0.04f;  // f32 cast of python double 0.2**2 — NOT 0.2f*0.2f

    int* out  = gidx + (size_t)q * NSAMPLE;
    int taken = 0;
    int first = NN - 1;

    for (int chunk = 0; chunk < NN / 64 && taken < NSAMPLE; ++chunk) {
        const int   i  = chunk * 64 + lane;
        const float dx = cx - bx[i * 3 + 0];
        const float dy = cy - bx[i * 3 + 1];
        const float dz = cz - bx[i * 3 + 2];
        const float t  = dx * dx + dy * dy + dz * dz;
        const bool ok  = !(t > rad2);
        const unsigned long long m = __ballot(ok);
        const int cnt = __popcll(m);
        if (taken == 0 && cnt > 0) first = chunk * 64 + (__ffsll((long long)m) - 1);
        if (ok) {
            const int rank = taken + __popcll(m & ((1ull << lane) - 1ull));
            if (rank < NSAMPLE) out[rank] = i;
        }
        taken += cnt;
    }
    const int sat = taken < NSAMPLE ? taken : NSAMPLE;
    if (lane >= sat && lane < NSAMPLE) out[lane] = (taken > 0) ? first : (NN - 1);
}

// ---------------------------------------------------------------------------
// K3: gather feats -> LDS, MLP1 (67->64) + relu, MLP2 (64->128) + relu,
// max over the 32 samples. One 256-thread block per query. FMA allowed.
// ---------------------------------------------------------------------------
__global__ __launch_bounds__(256) void mlp_kernel(const float* __restrict__ xyz,
                                                  const float* __restrict__ points,
                                                  const float* __restrict__ w1,
                                                  const float* __restrict__ b1,
                                                  const float* __restrict__ w2,
                                                  const float* __restrict__ b2,
                                                  const float* __restrict__ new_xyz,
                                                  const int*   __restrict__ gidx,
                                                  float* __restrict__ new_points) {
    __shared__ __align__(16) float feats[32][68];
    __shared__ __align__(16) float h1s[32][64];
    __shared__ float pmax[2][128];

    const int q = blockIdx.x;
    const int b = q >> 10;
    const int t = threadIdx.x;

    {
        const int k  = t >> 3;
        const int l8 = t & 7;
        const int gi = gidx[q * 32 + k];
        const float* prow = points + ((size_t)b * NN + gi) * CC;
        const float4 v0 = *(const float4*)(prow + l8 * 8);
        const float4 v1 = *(const float4*)(prow + l8 * 8 + 4);
        *(float4*)&feats[k][4 + l8 * 8] = v0;
        *(float4*)&feats[k][8 + l8 * 8] = v1;
        if (l8 == 0) {
            const float* pr = xyz + ((size_t)b * NN + gi) * 3;
            const float* nr = new_xyz + (size_t)q * 3;
            feats[k][0] = pr[0] - nr[0];
            feats[k][1] = pr[1] - nr[1];
            feats[k][2] = pr[2] - nr[2];
        }
    }

    const int c1 = t & 63;
    float w1r[67];
    #pragma unroll
    for (int j = 0; j < 67; ++j) w1r[j] = w1[c1 * 67 + j];
    const float bb1 = b1[c1];
    __syncthreads();

    const int kg = t >> 6;
    #pragma unroll
    for (int kk = 0; kk < 8; ++kk) {
        const int kr = kg * 8 + kk;
        float acc = bb1;
        acc += feats[kr][0] * w1r[0] + feats[kr][1] * w1r[1] + feats[kr][2] * w1r[2];
        #pragma unroll
        for (int j = 0; j < 64; j += 4) {
            const float4 f = *(const float4*)&feats[kr][4 + j];
            acc += f.x * w1r[3 + j] + f.y * w1r[4 + j] + f.z * w1r[5 + j] + f.w * w1r[6 + j];
        }
        h1s[kr][c1] = fmaxf(acc, 0.0f);
    }

    const int o2 = t & 127;
    const int kh = t >> 7;
    float w2r[64];
    #pragma unroll
    for (int j = 0; j < 64; ++j) w2r[j] = w2[o2 * 64 + j];
    const float bb2 = b2[o2];
    __syncthreads();

    float mx = -INFINITY;
    #pragma unroll
    for (int kk = 0; kk < 16; ++kk) {
        const int kr = kh * 16 + kk;
        float acc = bb2;
        #pragma unroll
        for (int j = 0; j < 64; j += 4) {
            const float4 h = *(const float4*)&h1s[kr][j];
            acc += h.x * w2r[j] + h.y * w2r[j + 1] + h.z * w2r[j + 2] + h.w * w2r[j + 3];
        }
        mx = fmaxf(mx, fmaxf(acc, 0.0f));
    }
    pmax[kh][o2] = mx;
    __syncthreads();
    if (t < 128) {
        new_points[(size_t)q * 128 + t] = fmaxf(pmax[0][t], pmax[1][t]);
    }
}

// ---------------------------------------------------------------------------
extern "C" void kernel_launch(void* const* d_in, const int* in_sizes, int n_in,
                              void* d_out, int out_size, void* d_ws, size_t ws_size,
                              hipStream_t stream) {
    const float* xyz    = (const float*)d_in[0];
    const float* points = (const float*)d_in[1];
    const float* w1     = (const float*)d_in[2];
    const float* b1     = (const float*)d_in[3];
    const float* w2     = (const float*)d_in[4];
    const float* b2     = (const float*)d_in[5];

    float* out_newxyz    = (float*)d_out;
    float* out_newpoints = (float*)d_out + (size_t)BB * NPOINT * 3;
    int*    gidx    = (int*)d_ws;                                   // 512 KB
    float4* sortbuf = (float4*)((char*)d_ws + (size_t)512 * 1024);  // 1 MB

    // LDS map: sxy 131072 | hist/outc alias @131072 (16384) | aabb @147456
    // (6528) | wbk @153984 (256) | wbc @154240 (512) | wsum @154752 (64)
    const int fps_lds = 154816;
    (void)hipFuncSetAttribute((const void*)fps_kernel,
                              hipFuncAttributeMaxDynamicSharedMemorySize,
                              fps_lds);

    fps_kernel<<<BB, FPS_T, fps_lds, stream>>>(xyz, out_newxyz, sortbuf);
    ballq_kernel<<<(BB * NPOINT) / 4, 256, 0, stream>>>(xyz, out_newxyz, gidx);
    mlp_kernel<<<BB * NPOINT, 256, 0, stream>>>(xyz, points, w1, b1, w2, b2,
                                                out_newxyz, gidx, out_newpoints);
}

// Round 11
// 1590.398 us; speedup vs baseline: 3.1641x; 1.1319x over previous
//
#include <hip/hip_runtime.h>

#define BB 4
#define NN 16384
#define CC 64
#define NPOINT 1024
#define NSAMPLE 32

#define FPS_T 1024
#define NCHUNK 256          // 64 points per chunk
#define NCELL 4096          // 16^3 Morton cells

#define REPEAT16(M) M(0) M(1) M(2) M(3) M(4) M(5) M(6) M(7) \
                    M(8) M(9) M(10) M(11) M(12) M(13) M(14) M(15)

// ---------------------------------------------------------------------------
// K1: Pruned FPS, 16 waves, event-driven reductions, atomic cross-wave
// reduce, no global ops in the iteration loop.
//  - Morton counting-sort: sb (global, float4 x,y,z,orig) + sxy (LDS float2).
//  - Wave wv owns chunks {wv+16k}; lane L holds u64 key##k =
//    d_bits<<32 | tb<<4 (tb = 0x3FFF-orig, globally unique) — LOOP-CARRIED.
//    z##k asm-pinned. AABB of chunk wv+16k in lane-k registers.
//  - Prune: chunk active iff mind2(AABB,c) <= min(prev_wd, cub)*1.001 where
//    cub = min over processed centroids of maxdist2(AABB,c) >= chunk max d
//    (maintained in the test itself, lane k). Exact-conservative skip.
//  - Event-driven: lane best recomputed only when its best's key decreased;
//    wave butterfly only when holder lane's best decreased. Unique keys ->
//    no tie paths; first-original-index tie-break exact.
//  - Cross-wave: holder writes coords to wbc dbuf + ONE atomicMax of
//    (bkey|wv) into slot[it&3]; ONE barrier; broadcast slot read -> wv ->
//    broadcast coords read. No butterfly in the fixed tail.
//  - Centroids buffered in LDS outc[], flushed after the loop (keeps vmcnt
//    out of the pre-barrier waitcnt).
// Bit-exact: contract(off), (dx*dx+dy*dy)+dz*dz order, min-as-cond-update.
// ---------------------------------------------------------------------------
__global__ __launch_bounds__(FPS_T) void fps_kernel(const float* __restrict__ xyz,
                                                    float* __restrict__ new_xyz,
                                                    float4* __restrict__ sorted) {
    #pragma clang fp contract(off)
    extern __shared__ char smem_raw[];
    float2* sxy  = (float2*)smem_raw;                         // 131072 B
    int*    hist = (int*)(smem_raw + 131072);                 // 16384 B (setup)
    float*  outc = (float*)(smem_raw + 131072);               // 12288 B (alias)
    float*  lox  = (float*)(smem_raw + 147456);               // 272 f x6
    float*  loy  = lox + 272;
    float*  loz  = loy + 272;
    float*  hix  = loz + 272;
    float*  hiy  = hix + 272;
    float*  hiz  = hiy + 272;
    float4* wbc  = (float4*)(smem_raw + 153984);              // [2][16] 512 B
    unsigned long long* slot = (unsigned long long*)(smem_raw + 154496); // [4]
    int*    wsum = (int*)(smem_raw + 154528);                 // [16]

    const int b    = blockIdx.x;
    const int tid  = threadIdx.x;
    const int lane = tid & 63;
    const int wv   = tid >> 6;                  // 0..15
    const float* bx = xyz + (size_t)b * NN * 3;
    float4* sb = sorted + (size_t)b * NN;

    // ---------- phase 0a: histogram of Morton cell codes ----------
    #pragma unroll
    for (int j = 0; j < 4; ++j) hist[j * FPS_T + tid] = 0;
    __syncthreads();

    #pragma unroll
    for (int j = 0; j < 16; ++j) {
        const int p = j * FPS_T + tid;
        const float x = bx[p * 3 + 0], y = bx[p * 3 + 1], z = bx[p * 3 + 2];
        int cx = (int)(x * 16.0f); cx = cx > 15 ? 15 : (cx < 0 ? 0 : cx);
        int cy = (int)(y * 16.0f); cy = cy > 15 ? 15 : (cy < 0 ? 0 : cy);
        int cz = (int)(z * 16.0f); cz = cz > 15 ? 15 : (cz < 0 ? 0 : cz);
        int code = 0;
        #pragma unroll
        for (int i = 0; i < 4; ++i)
            code |= (((cx >> i) & 1) << (3 * i)) |
                    (((cy >> i) & 1) << (3 * i + 1)) |
                    (((cz >> i) & 1) << (3 * i + 2));
        atomicAdd(&hist[code], 1);
    }
    __syncthreads();

    // ---------- phase 0b: exclusive scan ----------
    {
        const int h0 = hist[4 * tid + 0], h1 = hist[4 * tid + 1];
        const int h2 = hist[4 * tid + 2], h3 = hist[4 * tid + 3];
        const int s  = h0 + h1 + h2 + h3;
        int v = s;
        #pragma unroll
        for (int o = 1; o < 64; o <<= 1) {
            const int u = __shfl_up(v, o, 64);
            if (lane >= o) v += u;
        }
        if (lane == 63) wsum[wv] = v;
        __syncthreads();
        int base = 0;
        for (int w = 0; w < wv; ++w) base += wsum[w];
        const int e0 = base + v - s;
        hist[4 * tid + 0] = e0;
        hist[4 * tid + 1] = e0 + h0;
        hist[4 * tid + 2] = e0 + h0 + h1;
        hist[4 * tid + 3] = e0 + h0 + h1 + h2;
    }
    __syncthreads();

    // ---------- phase 0c: scatter to global sb AND LDS sxy ----------
    #pragma unroll
    for (int j = 0; j < 16; ++j) {
        const int p = j * FPS_T + tid;
        const float x = bx[p * 3 + 0], y = bx[p * 3 + 1], z = bx[p * 3 + 2];
        int cx = (int)(x * 16.0f); cx = cx > 15 ? 15 : (cx < 0 ? 0 : cx);
        int cy = (int)(y * 16.0f); cy = cy > 15 ? 15 : (cy < 0 ? 0 : cy);
        int cz = (int)(z * 16.0f); cz = cz > 15 ? 15 : (cz < 0 ? 0 : cz);
        int code = 0;
        #pragma unroll
        for (int i = 0; i < 4; ++i)
            code |= (((cx >> i) & 1) << (3 * i)) |
                    (((cy >> i) & 1) << (3 * i + 1)) |
                    (((cz >> i) & 1) << (3 * i + 2));
        const int slotg = atomicAdd(&hist[code], 1);
        sb[slotg]  = make_float4(x, y, z, __int_as_float(p));
        sxy[slotg] = make_float2(x, y);
    }
    __syncthreads();   // drains scatter stores before readback

    // ---------- phase 0d: per-chunk AABB + z/key preload ----------
#define DECLZ(k) float z##k; unsigned long long key##k;
    REPEAT16(DECLZ)
#undef DECLZ
    float abx0 = 0.f, aby0 = 0.f, abz0 = 0.f, abx1 = 0.f, aby1 = 0.f, abz1 = 0.f;

#define AABBPRE(k) { const int g = wv + ((k) << 4);                       \
    const float4 pt = sb[(g << 6) + lane];                                \
    z##k = pt.z;                                                          \
    key##k = (((unsigned long long)__float_as_uint(1e10f)) << 32) |       \
             ((unsigned long long)(0x3FFFu -                              \
                    (unsigned)__float_as_int(pt.w)) << 4);                \
    float mnx = pt.x, mxx = pt.x, mny = pt.y, mxy = pt.y,                 \
          mnz = pt.z, mxz = pt.z;                                         \
    _Pragma("unroll")                                                     \
    for (int m = 32; m >= 1; m >>= 1) {                                   \
        mnx = fminf(mnx, __shfl_xor(mnx, m, 64));                         \
        mxx = fmaxf(mxx, __shfl_xor(mxx, m, 64));                         \
        mny = fminf(mny, __shfl_xor(mny, m, 64));                         \
        mxy = fmaxf(mxy, __shfl_xor(mxy, m, 64));                         \
        mnz = fminf(mnz, __shfl_xor(mnz, m, 64));                         \
        mxz = fmaxf(mxz, __shfl_xor(mxz, m, 64));                         \
    }                                                                     \
    if (lane == (k)) { abx0 = mnx; abx1 = mxx; aby0 = mny; aby1 = mxy;    \
                       abz0 = mnz; abz1 = mxz; } }
    REPEAT16(AABBPRE)
#undef AABBPRE
    if (tid == 0) { slot[0] = 0ull; slot[1] = 0ull; slot[2] = 0ull; slot[3] = 0ull; }
    __syncthreads();

    // ---------- main loop ----------
    unsigned long long bkey = 0ull;   // my lane best (max over key0..15)
    int bestk = 0;
    int holder_ln = 0;                // wave-uniform
    float hx = 0.f, hy = 0.f, hz = 0.f;
    float cub = 1e10f;                // lane k: upper bound on chunk max d

    float ccx = bx[0], ccy = bx[1], ccz = bx[2];
    float prev_wd = 1e10f;

    for (int it = 0; it < NPOINT; ++it) {
        asm volatile("" : "+v"(z0), "+v"(z1), "+v"(z2),  "+v"(z3),
                          "+v"(z4), "+v"(z5), "+v"(z6),  "+v"(z7),
                          "+v"(z8), "+v"(z9), "+v"(z10), "+v"(z11),
                          "+v"(z12), "+v"(z13), "+v"(z14), "+v"(z15));

        if (tid == 0) {
            outc[it * 3 + 0] = ccx;
            outc[it * 3 + 1] = ccy;
            outc[it * 3 + 2] = ccz;
        }

        // --- AABB prune + cub maintenance (lane k -> chunk wv+16k) ---
        bool active = false;
        if (lane < 16) {
            const float dxl = fmaxf(fmaxf(abx0 - ccx, ccx - abx1), 0.0f);
            const float dyl = fmaxf(fmaxf(aby0 - ccy, ccy - aby1), 0.0f);
            const float dzl = fmaxf(fmaxf(abz0 - ccz, ccz - abz1), 0.0f);
            const float mind2 = dxl * dxl + dyl * dyl + dzl * dzl;
            const float bound = fminf(prev_wd, cub);
            active = !(mind2 > bound * 1.001f);
            if (active) {
                // chunk will be processed with this centroid: tighten cub
                const float dxm = fmaxf(ccx - abx0, abx1 - ccx);
                const float dym = fmaxf(ccy - aby0, aby1 - ccy);
                const float dzm = fmaxf(ccz - abz0, abz1 - ccz);
                const float maxd2 = dxm * dxm + dym * dym + dzm * dzm;
                cub = fminf(cub, maxd2);
            }
        }
        const unsigned amask = (unsigned)(__ballot(active) & 0xFFFFull);

        bool lredo = false;
#define UPD(k) if (amask & (1u << (k))) {                                 \
            const int g = wv + ((k) << 4);                                \
            const float2 xy = sxy[(g << 6) + lane];                       \
            const float dx = xy.x - ccx;                                  \
            const float dy = xy.y - ccy;                                  \
            const float dz = z##k - ccz;                                  \
            const float t  = (dx * dx + dy * dy) + dz * dz;               \
            const float dold = __uint_as_float((unsigned)(key##k >> 32)); \
            if (t < dold) {                                               \
                key##k = (((unsigned long long)__float_as_uint(t)) << 32) \
                         | (key##k & 0xFFFFFFFFull);                      \
                lredo |= ((k) == bestk);                                  \
            }                                                             \
        }
        if (amask & 0x000Fu) { UPD(0)  UPD(1)  UPD(2)  UPD(3)  }
        if (amask & 0x00F0u) { UPD(4)  UPD(5)  UPD(6)  UPD(7)  }
        if (amask & 0x0F00u) { UPD(8)  UPD(9)  UPD(10) UPD(11) }
        if (amask & 0xF000u) { UPD(12) UPD(13) UPD(14) UPD(15) }
#undef UPD

        // --- per-lane best: recompute only when invalidated ---
        if (lredo) {
            bkey = 0ull; bestk = 0;
#define LM(k) if (key##k > bkey) { bkey = key##k; bestk = (k); }
            REPEAT16(LM)
#undef LM
        }

        // --- wave best: butterfly only when holder's best decreased ---
        const unsigned long long rb = __ballot(lredo);
        if ((rb >> holder_ln) & 1ull) {
            unsigned long long m = bkey;
            #pragma unroll
            for (int s = 32; s >= 1; s >>= 1) {
                const unsigned long long o = __shfl_xor(m, s, 64);
                m = o > m ? o : m;
            }
            holder_ln = __ffsll((long long)__ballot(bkey == m)) - 1;  // unique
            if (lane == holder_ln) {
                const float2 xy = sxy[((wv + (bestk << 4)) << 6) + lane];
                float zz = z0;
#define ZS(k) zz = (bestk == (k)) ? z##k : zz;
                REPEAT16(ZS)
#undef ZS
                hx = xy.x; hy = xy.y; hz = zz;
            }
        }

        // --- cross-wave: coords write + ONE atomicMax; ONE barrier ---
        if (lane == holder_ln) {
            wbc[(it & 1) * 16 + wv] = make_float4(hx, hy, hz, 0.0f);
            atomicMax(&slot[it & 3], bkey | (unsigned long long)wv);
        }
        if (tid == 0) slot[(it + 1) & 3] = 0ull;
        __syncthreads();

        // --- winner: broadcast slot read -> wv -> broadcast coords read ---
        const unsigned long long wk = slot[it & 3];
        prev_wd = __uint_as_float((unsigned)(wk >> 32));
        const int wwv = (int)(wk & 0xFull);
        const float4 wf = wbc[(it & 1) * 16 + wwv];
        ccx = wf.x; ccy = wf.y; ccz = wf.z;
    }

    // ---------- flush centroids ----------
    __syncthreads();
    float* outb = new_xyz + (size_t)b * NPOINT * 3;
    #pragma unroll
    for (int j = 0; j < 3; ++j) {
        const int idx = j * FPS_T + tid;
        outb[idx] = outc[idx];
    }
}

// ---------------------------------------------------------------------------
// K2: Ball query. One wave per query; ordered first-32 selection via ballot,
// early exit once 32 found. Exact arithmetic (contract off, rad2 = (float)0.04).
// ---------------------------------------------------------------------------
__global__ __launch_bounds__(256) void ballq_kernel(const float* __restrict__ xyz,
                                                    const float* __restrict__ new_xyz,
                                                    int* __restrict__ gidx) {
    #pragma clang fp contract(off)
    const int lane = threadIdx.x & 63;
    const int q    = blockIdx.x * 4 + (threadIdx.x >> 6);
    const int b    = q >> 10;                  // NPOINT = 1024
    const float* bx = xyz + (size_t)b * NN * 3;
    const float* nx = new_xyz + (size_t)q * 3;
    const float cx = nx[0], cy = nx[1], cz = nx[2];
    const float rad2 = 0.04f;  // f32 cast of python double 0.2**2 — NOT 0.2f*0.2f

    int* out  = gidx + (size_t)q * NSAMPLE;
    int taken = 0;
    int first = NN - 1;

    for (int chunk = 0; chunk < NN / 64 && taken < NSAMPLE; ++chunk) {
        const int   i  = chunk * 64 + lane;
        const float dx = cx - bx[i * 3 + 0];
        const float dy = cy - bx[i * 3 + 1];
        const float dz = cz - bx[i * 3 + 2];
        const float t  = dx * dx + dy * dy + dz * dz;
        const bool ok  = !(t > rad2);
        const unsigned long long m = __ballot(ok);
        const int cnt = __popcll(m);
        if (taken == 0 && cnt > 0) first = chunk * 64 + (__ffsll((long long)m) - 1);
        if (ok) {
            const int rank = taken + __popcll(m & ((1ull << lane) - 1ull));
            if (rank < NSAMPLE) out[rank] = i;
        }
        taken += cnt;
    }
    const int sat = taken < NSAMPLE ? taken : NSAMPLE;
    if (lane >= sat && lane < NSAMPLE) out[lane] = (taken > 0) ? first : (NN - 1);
}

// ---------------------------------------------------------------------------
// K3: gather feats -> LDS, MLP1 (67->64) + relu, MLP2 (64->128) + relu,
// max over the 32 samples. One 256-thread block per query. FMA allowed.
// ---------------------------------------------------------------------------
__global__ __launch_bounds__(256) void mlp_kernel(const float* __restrict__ xyz,
                                                  const float* __restrict__ points,
                                                  const float* __restrict__ w1,
                                                  const float* __restrict__ b1,
                                                  const float* __restrict__ w2,
                                                  const float* __restrict__ b2,
                                                  const float* __restrict__ new_xyz,
                                                  const int*   __restrict__ gidx,
                                                  float* __restrict__ new_points) {
    __shared__ __align__(16) float feats[32][68];
    __shared__ __align__(16) float h1s[32][64];
    __shared__ float pmax[2][128];

    const int q = blockIdx.x;
    const int b = q >> 10;
    const int t = threadIdx.x;

    {
        const int k  = t >> 3;
        const int l8 = t & 7;
        const int gi = gidx[q * 32 + k];
        const float* prow = points + ((size_t)b * NN + gi) * CC;
        const float4 v0 = *(const float4*)(prow + l8 * 8);
        const float4 v1 = *(const float4*)(prow + l8 * 8 + 4);
        *(float4*)&feats[k][4 + l8 * 8] = v0;
        *(float4*)&feats[k][8 + l8 * 8] = v1;
        if (l8 == 0) {
            const float* pr = xyz + ((size_t)b * NN + gi) * 3;
            const float* nr = new_xyz + (size_t)q * 3;
            feats[k][0] = pr[0] - nr[0];
            feats[k][1] = pr[1] - nr[1];
            feats[k][2] = pr[2] - nr[2];
        }
    }

    const int c1 = t & 63;
    float w1r[67];
    #pragma unroll
    for (int j = 0; j < 67; ++j) w1r[j] = w1[c1 * 67 + j];
    const float bb1 = b1[c1];
    __syncthreads();

    const int kg = t >> 6;
    #pragma unroll
    for (int kk = 0; kk < 8; ++kk) {
        const int kr = kg * 8 + kk;
        float acc = bb1;
        acc += feats[kr][0] * w1r[0] + feats[kr][1] * w1r[1] + feats[kr][2] * w1r[2];
        #pragma unroll
        for (int j = 0; j < 64; j += 4) {
            const float4 f = *(const float4*)&feats[kr][4 + j];
            acc += f.x * w1r[3 + j] + f.y * w1r[4 + j] + f.z * w1r[5 + j] + f.w * w1r[6 + j];
        }
        h1s[kr][c1] = fmaxf(acc, 0.0f);
    }

    const int o2 = t & 127;
    const int kh = t >> 7;
    float w2r[64];
    #pragma unroll
    for (int j = 0; j < 64; ++j) w2r[j] = w2[o2 * 64 + j];
    const float bb2 = b2[o2];
    __syncthreads();

    float mx = -INFINITY;
    #pragma unroll
    for (int kk = 0; kk < 16; ++kk) {
        const int kr = kh * 16 + kk;
        float acc = bb2;
        #pragma unroll
        for (int j = 0; j < 64; j += 4) {
            const float4 h = *(const float4*)&h1s[kr][j];
            acc += h.x * w2r[j] + h.y * w2r[j + 1] + h.z * w2r[j + 2] + h.w * w2r[j + 3];
        }
        mx = fmaxf(mx, fmaxf(acc, 0.0f));
    }
    pmax[kh][o2] = mx;
    __syncthreads();
    if (t < 128) {
        new_points[(size_t)q * 128 + t] = fmaxf(pmax[0][t], pmax[1][t]);
    }
}

// ---------------------------------------------------------------------------
extern "C" void kernel_launch(void* const* d_in, const int* in_sizes, int n_in,
                              void* d_out, int out_size, void* d_ws, size_t ws_size,
                              hipStream_t stream) {
    const float* xyz    = (const float*)d_in[0];
    const float* points = (const float*)d_in[1];
    const float* w1     = (const float*)d_in[2];
    const float* b1     = (const float*)d_in[3];
    const float* w2     = (const float*)d_in[4];
    const float* b2     = (const float*)d_in[5];

    float* out_newxyz    = (float*)d_out;
    float* out_newpoints = (float*)d_out + (size_t)BB * NPOINT * 3;
    int*    gidx    = (int*)d_ws;                                   // 512 KB
    float4* sortbuf = (float4*)((char*)d_ws + (size_t)512 * 1024);  // 1 MB

    // LDS map: sxy 131072 | hist/outc alias @131072 (16384) | aabb @147456
    // (6528) | wbc @153984 (512) | slot @154496 (32) | wsum @154528 (64)
    const int fps_lds = 154816;
    (void)hipFuncSetAttribute((const void*)fps_kernel,
                              hipFuncAttributeMaxDynamicSharedMemorySize,
                              fps_lds);

    fps_kernel<<<BB, FPS_T, fps_lds, stream>>>(xyz, out_newxyz, sortbuf);
    ballq_kernel<<<(BB * NPOINT) / 4, 256, 0, stream>>>(xyz, out_newxyz, gidx);
    mlp_kernel<<<BB * NPOINT, 256, 0, stream>>>(xyz, points, w1, b1, w2, b2,
                                                out_newxyz, gidx, out_newpoints);
}